// Round 1
// baseline (844.799 us; speedup 1.0000x reference)
//
#include <hip/hip_runtime.h>
#include <hip/hip_bf16.h>
#include <stdint.h>

#define NN 50000
#define NE 800000
#define D 128
#define KH 3
#define LDH 512              // 4 hop slices * 128 per channel, bf16
#define WB_PER_J (256 * 512) // Wbig per channel: [c=256][k=512]

typedef __attribute__((ext_vector_type(8))) __bf16 bf16x8;
typedef __attribute__((ext_vector_type(4))) float f32x4;

__device__ __forceinline__ uint16_t bf16_rne(float f) {
  uint32_t u = __builtin_bit_cast(uint32_t, f);
  u = (u + 0x7fffu + ((u >> 16) & 1u)) >> 16;
  return (uint16_t)u;
}

// async global->LDS, 16B per lane; LDS dest is wave-uniform base + lane*16
#define GLDS16(gp, lp)                                                         \
  __builtin_amdgcn_global_load_lds(                                            \
      (__attribute__((address_space(1))) void*)(gp),                           \
      (__attribute__((address_space(3))) void*)(lp), 16, 0, 0)

__global__ void k_deg(const int* __restrict__ row, int* __restrict__ deg) {
  int e = blockIdx.x * 256 + threadIdx.x;
  if (e < NE) atomicAdd(&deg[row[e]], 1);
}

__global__ void k_dinv(const int* __restrict__ deg, float* __restrict__ dinv) {
  int i = blockIdx.x * 256 + threadIdx.x;
  if (i < NN) {
    int d = deg[i];
    dinv[i] = (d > 0) ? rsqrtf((float)d) : 0.0f;
  }
}

// single-block two-level exclusive scan of deg -> row_ptr (+ cursor copy)
__global__ void k_scan(const int* __restrict__ deg, int* __restrict__ rp,
                       int* __restrict__ cur) {
  __shared__ int ss[1024];
  const int CH = (NN + 1023) / 1024; // 49
  int t = threadIdx.x;
  int b = t * CH;
  int e = min(b + CH, NN);
  int s = 0;
  for (int i = b; i < e; ++i) s += deg[i];
  ss[t] = s;
  __syncthreads();
  for (int off = 1; off < 1024; off <<= 1) {
    int v = (t >= off) ? ss[t - off] : 0;
    __syncthreads();
    ss[t] += v;
    __syncthreads();
  }
  int run = ss[t] - s; // exclusive prefix of this thread's chunk
  for (int i = b; i < e; ++i) {
    rp[i] = run;
    cur[i] = run;
    run += deg[i];
  }
  if (t == 1023) rp[NN] = run; // = NE
}

__global__ void k_scatter(const int* __restrict__ row, const int* __restrict__ col,
                          const float* __restrict__ dinv, int* __restrict__ cur,
                          int2* __restrict__ csr) {
  int e = blockIdx.x * 256 + threadIdx.x;
  if (e < NE) {
    int r = row[e], c = col[e];
    int pos = atomicAdd(&cur[r], 1);
    csr[pos] = make_int2(c, __float_as_int(dinv[r] * dinv[c]));
  }
}

// Wbig^T[j][c=i*128+f][k=m*128+d] = bf16(params[i,j,m] * W[i,j,d,f])
__global__ void k_wbig(const float* __restrict__ W, const float* __restrict__ params,
                       uint16_t* __restrict__ wb) {
  int idx = blockIdx.x * 256 + threadIdx.x;
  if (idx >= 2 * WB_PER_J) return;
  int j = idx >> 17, c = (idx >> 9) & 255, k = idx & 511;
  int i = c >> 7, f = c & 127, m = k >> 7, dd = k & 127;
  float p = params[(i * 2 + j) * 4 + m];
  float w = W[((i * 2 + j) * 128 + dd) * 128 + f];
  wb[idx] = bf16_rne(p * w);
}

// hop-0 slice: H[n][0:128] = bf16(x[j][n][:])
__global__ void k_x2h(const float* __restrict__ x, uint16_t* __restrict__ H) {
  int idx = blockIdx.x * 256 + threadIdx.x;
  if (idx >= NN * D) return;
  int n = idx >> 7, dd = idx & 127;
  H[(size_t)n * LDH + dd] = bf16_rne(x[idx]);
}

// one wave per row: H[:, m*128:...] = A_norm @ H[:, (m-1)*128:...]
__global__ void k_spmm(const int* __restrict__ rp, const int2* __restrict__ csr,
                       uint16_t* __restrict__ H, int m) {
  int wid = threadIdx.x >> 6, lane = threadIdx.x & 63;
  int r = blockIdx.x * 4 + wid;
  if (r >= NN) return;
  int s = rp[r], e = rp[r + 1];
  int inOff = (m - 1) * D + lane * 2;
  float a0 = 0.f, a1 = 0.f;
  for (int i = s; i < e; ++i) {
    int2 cv = csr[i];
    float val = __int_as_float(cv.y);
    uint32_t p = *(const uint32_t*)(H + (size_t)cv.x * LDH + inOff);
    a0 += val * __builtin_bit_cast(float, p << 16);
    a1 += val * __builtin_bit_cast(float, p & 0xffff0000u);
  }
  uint32_t o = ((uint32_t)bf16_rne(a1) << 16) | (uint32_t)bf16_rne(a0);
  *(uint32_t*)(H + (size_t)r * LDH + m * D + lane * 2) = o;
}

// C[m0:m0+128, c0:c0+128] = A[N,512] @ B^T[256,512]^T ; out col c -> (i=c>>7, f=c&127)
template <int ACCUM>
__global__ __launch_bounds__(256) void k_gemm(const uint16_t* __restrict__ A,
                                              const uint16_t* __restrict__ BT,
                                              float* __restrict__ out) {
  __shared__ __align__(16) uint16_t As[128 * 32]; // [row][k]
  __shared__ __align__(16) uint16_t Bs[128 * 32]; // [col][k]
  int t = threadIdx.x;
  int lane = t & 63, wid = t >> 6;
  int wm = wid >> 1, wn = wid & 1;
  int m0 = blockIdx.x * 128;
  int c0 = blockIdx.y * 128;
  int rl = lane & 15, kq = (lane >> 4) * 8;
  f32x4 acc[4][4] = {};
  for (int k0 = 0; k0 < 512; k0 += 32) {
#pragma unroll
    for (int rr = 0; rr < 2; ++rr) { // stage A tile: 512 chunks of 16B
      int c = rr * 256 + t;
      int row = c >> 2, kc = c & 3;
      int gr = m0 + row;
      gr = gr < NN ? gr : NN - 1; // clamp (dup row is harmless, store guarded)
      GLDS16(A + (size_t)gr * LDH + k0 + kc * 8, &As[c * 8]);
    }
#pragma unroll
    for (int rr = 0; rr < 2; ++rr) { // stage B tile
      int c = rr * 256 + t;
      int cc = c >> 2, kc = c & 3;
      GLDS16(BT + (size_t)(c0 + cc) * 512 + k0 + kc * 8, &Bs[c * 8]);
    }
    __syncthreads();
    bf16x8 af[4], bq[4];
#pragma unroll
    for (int f = 0; f < 4; ++f)
      af[f] = *(const bf16x8*)(&As[(wm * 64 + f * 16 + rl) * 32 + kq]);
#pragma unroll
    for (int f = 0; f < 4; ++f)
      bq[f] = *(const bf16x8*)(&Bs[(wn * 64 + f * 16 + rl) * 32 + kq]);
#pragma unroll
    for (int fm = 0; fm < 4; ++fm)
#pragma unroll
      for (int fn = 0; fn < 4; ++fn)
        acc[fm][fn] = __builtin_amdgcn_mfma_f32_16x16x32_bf16(af[fm], bq[fn],
                                                              acc[fm][fn], 0, 0, 0);
    __syncthreads();
  }
  int iOut = blockIdx.y;
#pragma unroll
  for (int fm = 0; fm < 4; ++fm) {
#pragma unroll
    for (int r = 0; r < 4; ++r) {
      int rowg = m0 + wm * 64 + fm * 16 + (lane >> 4) * 4 + r;
      if (rowg >= NN) continue;
      float* op = out + ((size_t)iOut * NN + rowg) * D;
#pragma unroll
      for (int fn = 0; fn < 4; ++fn) {
        int colg = wn * 64 + fn * 16 + rl;
        if (ACCUM)
          op[colg] += acc[fm][fn][r];
        else
          op[colg] = acc[fm][fn][r];
      }
    }
  }
}

extern "C" void kernel_launch(void* const* d_in, const int* in_sizes, int n_in,
                              void* d_out, int out_size, void* d_ws, size_t ws_size,
                              hipStream_t stream) {
  (void)in_sizes; (void)n_in; (void)out_size; (void)ws_size;
  const float* x = (const float*)d_in[0];      // [2, N, 128]
  const int* ei = (const int*)d_in[1];         // [2, E]
  const float* W = (const float*)d_in[2];      // [2, 2, 128, 128]
  const float* params = (const float*)d_in[3]; // [2, 2, 4]
  float* out = (float*)d_out;                  // [2, N, 128]
  char* ws = (char*)d_ws;

  size_t off = 0;
  auto take = [&](size_t bytes) {
    char* p = ws + off;
    off = (off + bytes + 255) & ~(size_t)255;
    return p;
  };
  int* deg = (int*)take((size_t)NN * 4);
  float* dinv = (float*)take((size_t)NN * 4);
  int* rp = (int*)take((size_t)(NN + 1) * 4);
  int* cur = (int*)take((size_t)NN * 4);
  int2* csr = (int2*)take((size_t)NE * 8);
  uint16_t* wb = (uint16_t*)take((size_t)2 * WB_PER_J * 2);
  uint16_t* H = (uint16_t*)take((size_t)NN * LDH * 2); // ~51.2 MB, reused per channel

  hipMemsetAsync(deg, 0, (size_t)NN * 4, stream);
  k_deg<<<(NE + 255) / 256, 256, 0, stream>>>(ei, deg);
  k_dinv<<<(NN + 255) / 256, 256, 0, stream>>>(deg, dinv);
  k_scan<<<1, 1024, 0, stream>>>(deg, rp, cur);
  k_scatter<<<(NE + 255) / 256, 256, 0, stream>>>(ei, ei + NE, dinv, cur, csr);
  k_wbig<<<(2 * WB_PER_J + 255) / 256, 256, 0, stream>>>(W, params, wb);

  for (int j = 0; j < 2; ++j) {
    k_x2h<<<(NN * D + 255) / 256, 256, 0, stream>>>(x + (size_t)j * NN * D, H);
    for (int m = 1; m <= KH; ++m)
      k_spmm<<<(NN + 3) / 4, 256, 0, stream>>>(rp, csr, H, m);
    dim3 grid((NN + 127) / 128, 2);
    if (j == 0)
      k_gemm<0><<<grid, 256, 0, stream>>>(H, wb, out);
    else
      k_gemm<1><<<grid, 256, 0, stream>>>(H, wb + WB_PER_J, out);
  }
}

// Round 2
// 523.080 us; speedup vs baseline: 1.6150x; 1.6150x over previous
//
#include <hip/hip_runtime.h>
#include <hip/hip_bf16.h>
#include <stdint.h>

#define NN 50000
#define NE 800000
#define D 128
#define KH 3
#define SCAN_B ((NN + 255) / 256) // 196

typedef __attribute__((ext_vector_type(8))) __bf16 bf16x8;
typedef __attribute__((ext_vector_type(4))) float f32x4;

__device__ __forceinline__ uint16_t bf16_rne(float f) {
  uint32_t u = __builtin_bit_cast(uint32_t, f);
  u = (u + 0x7fffu + ((u >> 16) & 1u)) >> 16;
  return (uint16_t)u;
}

// async global->LDS, 16B per lane; LDS dest is wave-uniform base + lane*16
#define GLDS16(gp, lp)                                                         \
  __builtin_amdgcn_global_load_lds(                                            \
      (__attribute__((address_space(1))) void*)(gp),                           \
      (__attribute__((address_space(3))) void*)(lp), 16, 0, 0)

__global__ void k_deg(const int* __restrict__ row, int* __restrict__ deg) {
  int e = blockIdx.x * 256 + threadIdx.x;
  if (e < NE) atomicAdd(&deg[row[e]], 1);
}

__global__ void k_dinv(const int* __restrict__ deg, float* __restrict__ dinv) {
  int i = blockIdx.x * 256 + threadIdx.x;
  if (i < NN) {
    int d = deg[i];
    dinv[i] = (d > 0) ? rsqrtf((float)d) : 0.0f;
  }
}

// ---- parallel 3-kernel scan (replaces the 109us single-block k_scan) ----
__global__ void k_bsum(const int* __restrict__ deg, int* __restrict__ bsum) {
  __shared__ int s[256];
  int t = threadIdx.x;
  int i = blockIdx.x * 256 + t;
  s[t] = (i < NN) ? deg[i] : 0;
  __syncthreads();
  for (int off = 128; off > 0; off >>= 1) {
    if (t < off) s[t] += s[t + off];
    __syncthreads();
  }
  if (t == 0) bsum[blockIdx.x] = s[0];
}

__global__ void k_bscan(const int* __restrict__ bsum, int* __restrict__ boff) {
  __shared__ int s[256];
  int t = threadIdx.x;
  int v = (t < SCAN_B) ? bsum[t] : 0;
  s[t] = v;
  __syncthreads();
  for (int off = 1; off < 256; off <<= 1) {
    int u = (t >= off) ? s[t - off] : 0;
    __syncthreads();
    s[t] += u;
    __syncthreads();
  }
  boff[t] = s[t] - v; // exclusive
}

__global__ void k_rpwrite(const int* __restrict__ deg, const int* __restrict__ boff,
                          int* __restrict__ rp, int* __restrict__ cur) {
  __shared__ int s[256];
  int t = threadIdx.x;
  int i = blockIdx.x * 256 + t;
  int v = (i < NN) ? deg[i] : 0;
  s[t] = v;
  __syncthreads();
  for (int off = 1; off < 256; off <<= 1) {
    int u = (t >= off) ? s[t - off] : 0;
    __syncthreads();
    s[t] += u;
    __syncthreads();
  }
  if (i < NN) {
    int r = boff[blockIdx.x] + s[t] - v;
    rp[i] = r;
    cur[i] = r;
  }
  if (i == 0) rp[NN] = NE;
}

__global__ void k_scatter(const int* __restrict__ row, const int* __restrict__ col,
                          const float* __restrict__ dinv, int* __restrict__ cur,
                          int2* __restrict__ csr) {
  int e = blockIdx.x * 256 + threadIdx.x;
  if (e < NE) {
    int r = row[e], c = col[e];
    int pos = atomicAdd(&cur[r], 1);
    csr[pos] = make_int2(c, __float_as_int(dinv[r] * dinv[c]));
  }
}

// ---- weight prep ----
// combined: wb[c=256][k=1024], k -> m=k>>8, j=(k>>7)&1, d=k&127; c -> i=c>>7, f=c&127
__global__ void k_wbig_c(const float* __restrict__ W, const float* __restrict__ params,
                         uint16_t* __restrict__ wb) {
  int idx = blockIdx.x * 256 + threadIdx.x;
  if (idx >= 256 * 1024) return;
  int c = idx >> 10, k = idx & 1023;
  int i = c >> 7, f = c & 127, m = k >> 8, j = (k >> 7) & 1, dd = k & 127;
  float p = params[(i * 2 + j) * 4 + m];
  float w = W[((i * 2 + j) * 128 + dd) * 128 + f];
  wb[idx] = bf16_rne(p * w);
}

// fallback: wb[j][c=256][k=512], k -> m=k>>7, d=k&127
__global__ void k_wbig_f(const float* __restrict__ W, const float* __restrict__ params,
                         uint16_t* __restrict__ wb) {
  int idx = blockIdx.x * 256 + threadIdx.x;
  if (idx >= 2 * 256 * 512) return;
  int j = idx >> 17, c = (idx >> 9) & 255, k = idx & 511;
  int i = c >> 7, f = c & 127, m = k >> 7, dd = k & 127;
  float p = params[(i * 2 + j) * 4 + m];
  float w = W[((i * 2 + j) * 128 + dd) * 128 + f];
  wb[idx] = bf16_rne(p * w);
}

// ---- hop-0 conversion ----
// combined: dst[n][j*128+d] = bf16(x[j][n][d]); dst row stride 256
__global__ void k_x2h_c(const float* __restrict__ x, uint16_t* __restrict__ dst) {
  int idx = blockIdx.x * 256 + threadIdx.x;
  if (idx >= NN * 256) return;
  int n = idx >> 8, c = idx & 255, j = c >> 7, dd = c & 127;
  dst[idx] = bf16_rne(x[(size_t)j * NN * D + (size_t)n * D + dd]);
}

// fallback: dst[n][d] = bf16(xj[n][d]); row stride 128
__global__ void k_x2h_f(const float* __restrict__ xj, uint16_t* __restrict__ dst) {
  int idx = blockIdx.x * 256 + threadIdx.x;
  if (idx < NN * D) dst[idx] = bf16_rne(xj[idx]);
}

// ---- SpMM: dst = A_norm @ src, row stride NCH*128; one wave per row ----
template <int NCH>
__global__ void k_spmm(const int* __restrict__ rp, const int2* __restrict__ csr,
                       const uint16_t* __restrict__ src, uint16_t* __restrict__ dst) {
  int wid = threadIdx.x >> 6, lane = threadIdx.x & 63;
  int r = blockIdx.x * 4 + wid;
  if (r >= NN) return;
  int s = rp[r], e = rp[r + 1];
  const int stride = NCH * 128;
  float a[2 * NCH] = {};
  for (int i = s; i < e; ++i) {
    int2 cv = csr[i];
    float val = __int_as_float(cv.y);
    const uint16_t* base = src + (size_t)cv.x * stride + lane * 2;
#pragma unroll
    for (int c = 0; c < NCH; ++c) {
      uint32_t p = *(const uint32_t*)(base + c * 128);
      a[2 * c] += val * __builtin_bit_cast(float, p << 16);
      a[2 * c + 1] += val * __builtin_bit_cast(float, p & 0xffff0000u);
    }
  }
  uint16_t* ob = dst + (size_t)r * stride + lane * 2;
#pragma unroll
  for (int c = 0; c < NCH; ++c) {
    uint32_t o = ((uint32_t)bf16_rne(a[2 * c + 1]) << 16) | (uint32_t)bf16_rne(a[2 * c]);
    *(uint32_t*)(ob + c * 128) = o;
  }
}

// ---- GEMM: out[i*NN+n][f] (+)= sum_k A[n][k] * wb[i*128+f][k] ----
// A row n, k -> hop = k/HOPW, inner = k%HOPW, at hop_ptr + n*HOPW + inner
template <int KTOT, int HOPW, int ACCUM>
__global__ __launch_bounds__(256) void k_gemm(
    const uint16_t* __restrict__ h0, const uint16_t* __restrict__ h1,
    const uint16_t* __restrict__ h2, const uint16_t* __restrict__ h3,
    const uint16_t* __restrict__ wb, float* __restrict__ out) {
  __shared__ __align__(16) uint16_t As[128 * 32]; // [row][k]
  __shared__ __align__(16) uint16_t Bs[128 * 32]; // [col][k]
  int t = threadIdx.x;
  int lane = t & 63, wid = t >> 6;
  int wm = wid >> 1, wn = wid & 1;
  int m0 = blockIdx.x * 128;
  int c0 = blockIdx.y * 128;
  int rl = lane & 15, kq = (lane >> 4) * 8;
  f32x4 acc[4][4] = {};
  for (int k0 = 0; k0 < KTOT; k0 += 32) {
    int hop = k0 / HOPW, kin = k0 % HOPW;
    const uint16_t* hm = hop == 0 ? h0 : hop == 1 ? h1 : hop == 2 ? h2 : h3;
#pragma unroll
    for (int rr = 0; rr < 2; ++rr) { // stage A tile: 512 chunks of 16B
      int c = rr * 256 + t;
      int row = c >> 2, kc = c & 3;
      int gr = m0 + row;
      gr = gr < NN ? gr : NN - 1; // clamp (dup row harmless, store guarded)
      GLDS16(hm + (size_t)gr * HOPW + kin + kc * 8, &As[c * 8]);
    }
#pragma unroll
    for (int rr = 0; rr < 2; ++rr) { // stage B tile
      int c = rr * 256 + t;
      int cc = c >> 2, kc = c & 3;
      GLDS16(wb + (size_t)(c0 + cc) * KTOT + k0 + kc * 8, &Bs[c * 8]);
    }
    __syncthreads();
    bf16x8 af[4], bq[4];
#pragma unroll
    for (int f = 0; f < 4; ++f)
      af[f] = *(const bf16x8*)(&As[(wm * 64 + f * 16 + rl) * 32 + kq]);
#pragma unroll
    for (int f = 0; f < 4; ++f)
      bq[f] = *(const bf16x8*)(&Bs[(wn * 64 + f * 16 + rl) * 32 + kq]);
#pragma unroll
    for (int fm = 0; fm < 4; ++fm)
#pragma unroll
      for (int fn = 0; fn < 4; ++fn)
        acc[fm][fn] = __builtin_amdgcn_mfma_f32_16x16x32_bf16(af[fm], bq[fn],
                                                              acc[fm][fn], 0, 0, 0);
    __syncthreads();
  }
  int iOut = blockIdx.y;
#pragma unroll
  for (int fm = 0; fm < 4; ++fm) {
#pragma unroll
    for (int r = 0; r < 4; ++r) {
      int rowg = m0 + wm * 64 + fm * 16 + (lane >> 4) * 4 + r;
      if (rowg >= NN) continue;
      float* op = out + ((size_t)iOut * NN + rowg) * D;
#pragma unroll
      for (int fn = 0; fn < 4; ++fn) {
        int colg = wn * 64 + fn * 16 + rl;
        if (ACCUM)
          op[colg] += acc[fm][fn][r];
        else
          op[colg] = acc[fm][fn][r];
      }
    }
  }
}

extern "C" void kernel_launch(void* const* d_in, const int* in_sizes, int n_in,
                              void* d_out, int out_size, void* d_ws, size_t ws_size,
                              hipStream_t stream) {
  (void)in_sizes; (void)n_in; (void)out_size;
  const float* x = (const float*)d_in[0];      // [2, N, 128]
  const int* ei = (const int*)d_in[1];         // [2, E]
  const float* W = (const float*)d_in[2];      // [2, 2, 128, 128]
  const float* params = (const float*)d_in[3]; // [2, 2, 4]
  float* out = (float*)d_out;                  // [2, N, 128]
  char* ws = (char*)d_ws;

  size_t off = 0;
  auto take = [&](size_t bytes) {
    char* p = ws + off;
    off = (off + bytes + 255) & ~(size_t)255;
    return p;
  };
  int* deg = (int*)take((size_t)NN * 4);
  float* dinv = (float*)take((size_t)NN * 4);
  int* rp = (int*)take((size_t)(NN + 1) * 4);
  int* cur = (int*)take((size_t)NN * 4);
  int* bsum = (int*)take(256 * 4);
  int* boff = (int*)take(256 * 4);
  int2* csr = (int2*)take((size_t)NE * 8);
  uint16_t* wb = (uint16_t*)take((size_t)256 * 1024 * 2); // 512 KB (both layouts fit)
  size_t fixed = off;

  // shared CSR-build + weight-agnostic prologue
  hipMemsetAsync(deg, 0, (size_t)NN * 4, stream);
  k_deg<<<(NE + 255) / 256, 256, 0, stream>>>(ei, deg);
  k_dinv<<<(NN + 255) / 256, 256, 0, stream>>>(deg, dinv);
  k_bsum<<<SCAN_B, 256, 0, stream>>>(deg, bsum);
  k_bscan<<<1, 256, 0, stream>>>(bsum, boff);
  k_rpwrite<<<SCAN_B, 256, 0, stream>>>(deg, boff, rp, cur);
  k_scatter<<<(NE + 255) / 256, 256, 0, stream>>>(ei, ei + NE, dinv, cur, csr);

  size_t hopC = (size_t)NN * 256 * 2; // 25.6 MB per hop, combined channels
  size_t needC = fixed + 4 * hopC + 1024;

  if (ws_size >= needC) {
    // ---- fused-channel path: 3 spmm + 1 GEMM (K=1024) ----
    uint16_t* hop[4];
    for (int m = 0; m < 4; ++m) hop[m] = (uint16_t*)take(hopC);
    k_wbig_c<<<(256 * 1024 + 255) / 256, 256, 0, stream>>>(W, params, wb);
    k_x2h_c<<<(NN * 256 + 255) / 256, 256, 0, stream>>>(x, hop[0]);
    for (int m = 1; m <= KH; ++m)
      k_spmm<2><<<(NN + 3) / 4, 256, 0, stream>>>(rp, csr, hop[m - 1], hop[m]);
    dim3 grid((NN + 127) / 128, 2);
    k_gemm<1024, 256, 0><<<grid, 256, 0, stream>>>(hop[0], hop[1], hop[2], hop[3],
                                                   wb, out);
  } else {
    // ---- fallback: per-channel hops (round-1 footprint), 2 GEMMs ----
    size_t hopF = (size_t)NN * 128 * 2; // 12.8 MB
    uint16_t* hop[4];
    for (int m = 0; m < 4; ++m) hop[m] = (uint16_t*)take(hopF);
    k_wbig_f<<<(2 * 256 * 512 + 255) / 256, 256, 0, stream>>>(W, params, wb);
    for (int j = 0; j < 2; ++j) {
      k_x2h_f<<<(NN * D + 255) / 256, 256, 0, stream>>>(x + (size_t)j * NN * D, hop[0]);
      for (int m = 1; m <= KH; ++m)
        k_spmm<1><<<(NN + 3) / 4, 256, 0, stream>>>(rp, csr, hop[m - 1], hop[m]);
      dim3 grid((NN + 127) / 128, 2);
      if (j == 0)
        k_gemm<512, 128, 0><<<grid, 256, 0, stream>>>(hop[0], hop[1], hop[2], hop[3],
                                                      wb, out);
      else
        k_gemm<512, 128, 1><<<grid, 256, 0, stream>>>(hop[0], hop[1], hop[2], hop[3],
                                                      wb + 256 * 512, out);
    }
  }
}

// Round 3
// 422.038 us; speedup vs baseline: 2.0017x; 1.2394x over previous
//
#include <hip/hip_runtime.h>
#include <hip/hip_bf16.h>
#include <stdint.h>

#define NN 50000
#define NE 800000
#define D 128
#define KH 3
#define SCAN_B ((NN + 255) / 256) // 196

typedef __attribute__((ext_vector_type(8))) __bf16 bf16x8;
typedef __attribute__((ext_vector_type(4))) float f32x4;

__device__ __forceinline__ uint16_t bf16_rne(float f) {
  uint32_t u = __builtin_bit_cast(uint32_t, f);
  u = (u + 0x7fffu + ((u >> 16) & 1u)) >> 16;
  return (uint16_t)u;
}

// async global->LDS, 16B per lane; LDS dest is wave-uniform base + lane*16
#define GLDS16(gp, lp)                                                         \
  __builtin_amdgcn_global_load_lds(                                            \
      (__attribute__((address_space(1))) void*)(gp),                           \
      (__attribute__((address_space(3))) void*)(lp), 16, 0, 0)

__global__ void k_deg(const int* __restrict__ row, int* __restrict__ deg) {
  int e = blockIdx.x * 256 + threadIdx.x;
  if (e < NE) atomicAdd(&deg[row[e]], 1);
}

__global__ void k_dinv(const int* __restrict__ deg, float* __restrict__ dinv) {
  int i = blockIdx.x * 256 + threadIdx.x;
  if (i < NN) {
    int d = deg[i];
    dinv[i] = (d > 0) ? rsqrtf((float)d) : 0.0f;
  }
}

// ---- parallel 3-kernel scan ----
__global__ void k_bsum(const int* __restrict__ deg, int* __restrict__ bsum) {
  __shared__ int s[256];
  int t = threadIdx.x;
  int i = blockIdx.x * 256 + t;
  s[t] = (i < NN) ? deg[i] : 0;
  __syncthreads();
  for (int off = 128; off > 0; off >>= 1) {
    if (t < off) s[t] += s[t + off];
    __syncthreads();
  }
  if (t == 0) bsum[blockIdx.x] = s[0];
}

__global__ void k_bscan(const int* __restrict__ bsum, int* __restrict__ boff) {
  __shared__ int s[256];
  int t = threadIdx.x;
  int v = (t < SCAN_B) ? bsum[t] : 0;
  s[t] = v;
  __syncthreads();
  for (int off = 1; off < 256; off <<= 1) {
    int u = (t >= off) ? s[t - off] : 0;
    __syncthreads();
    s[t] += u;
    __syncthreads();
  }
  boff[t] = s[t] - v; // exclusive
}

__global__ void k_rpwrite(const int* __restrict__ deg, const int* __restrict__ boff,
                          int* __restrict__ rp, int* __restrict__ cur) {
  __shared__ int s[256];
  int t = threadIdx.x;
  int i = blockIdx.x * 256 + t;
  int v = (i < NN) ? deg[i] : 0;
  s[t] = v;
  __syncthreads();
  for (int off = 1; off < 256; off <<= 1) {
    int u = (t >= off) ? s[t - off] : 0;
    __syncthreads();
    s[t] += u;
    __syncthreads();
  }
  if (i < NN) {
    int r = boff[blockIdx.x] + s[t] - v;
    rp[i] = r;
    cur[i] = r;
  }
  if (i == 0) rp[NN] = NE;
}

__global__ void k_scatter(const int* __restrict__ row, const int* __restrict__ col,
                          const float* __restrict__ dinv, int* __restrict__ cur,
                          int2* __restrict__ csr) {
  int e = blockIdx.x * 256 + threadIdx.x;
  if (e < NE) {
    int r = row[e], c = col[e];
    int pos = atomicAdd(&cur[r], 1);
    csr[pos] = make_int2(c, __float_as_int(dinv[r] * dinv[c]));
  }
}

// ---- weight prep ----
// combined: wb[c=256][k=1024], k -> m=k>>8, j=(k>>7)&1, d=k&127; c -> i=c>>7, f=c&127
__global__ void k_wbig_c(const float* __restrict__ W, const float* __restrict__ params,
                         uint16_t* __restrict__ wb) {
  int idx = blockIdx.x * 256 + threadIdx.x;
  if (idx >= 256 * 1024) return;
  int c = idx >> 10, k = idx & 1023;
  int i = c >> 7, f = c & 127, m = k >> 8, j = (k >> 7) & 1, dd = k & 127;
  float p = params[(i * 2 + j) * 4 + m];
  float w = W[((i * 2 + j) * 128 + dd) * 128 + f];
  wb[idx] = bf16_rne(p * w);
}

// fallback: wb[j][c=256][k=512], k -> m=k>>7, d=k&127
__global__ void k_wbig_f(const float* __restrict__ W, const float* __restrict__ params,
                         uint16_t* __restrict__ wb) {
  int idx = blockIdx.x * 256 + threadIdx.x;
  if (idx >= 2 * 256 * 512) return;
  int j = idx >> 17, c = (idx >> 9) & 255, k = idx & 511;
  int i = c >> 7, f = c & 127, m = k >> 7, dd = k & 127;
  float p = params[(i * 2 + j) * 4 + m];
  float w = W[((i * 2 + j) * 128 + dd) * 128 + f];
  wb[idx] = bf16_rne(p * w);
}

// ---- hop-0 conversion ----
__global__ void k_x2h_c(const float* __restrict__ x, uint16_t* __restrict__ dst) {
  int idx = blockIdx.x * 256 + threadIdx.x;
  if (idx >= NN * 256) return;
  int n = idx >> 8, c = idx & 255, j = c >> 7, dd = c & 127;
  dst[idx] = bf16_rne(x[(size_t)j * NN * D + (size_t)n * D + dd]);
}

__global__ void k_x2h_f(const float* __restrict__ xj, uint16_t* __restrict__ dst) {
  int idx = blockIdx.x * 256 + threadIdx.x;
  if (idx < NN * D) dst[idx] = bf16_rne(xj[idx]);
}

// ---- SpMM: dst = A_norm @ src ----
// One wave per row. Lane covers NCH*2 consecutive bf16 (NCH dwords) of the
// NCH*128-elem row -> ONE dwordx{NCH} gather per edge per lane.
// Row extents scalarized via readfirstlane so csr[] reads become s_loads;
// edge loop unrolled x4 with batched loads -> 4 independent gathers in flight.
template <int NCH>
__global__ void k_spmm(const int* __restrict__ rp, const int2* __restrict__ csr,
                       const uint16_t* __restrict__ src, uint16_t* __restrict__ dst) {
  constexpr int STRIDE = NCH * 128; // elems per row
  typedef uint32_t gvec __attribute__((ext_vector_type(NCH)));
  const int lane = threadIdx.x & 63;
  const int wid = threadIdx.x >> 6;
  const int r = blockIdx.x * 4 + wid;
  if (r >= NN) return;
  const int s = __builtin_amdgcn_readfirstlane(rp[r]);
  const int e = __builtin_amdgcn_readfirstlane(rp[r + 1]);
  const int lo = lane * 2 * NCH; // first elem this lane covers

  float a[2 * NCH] = {};
  int i = s;
  for (; i + 4 <= e; i += 4) {
    int2 c0 = csr[i], c1 = csr[i + 1], c2 = csr[i + 2], c3 = csr[i + 3];
    gvec g0 = *(const gvec*)(src + (size_t)c0.x * STRIDE + lo);
    gvec g1 = *(const gvec*)(src + (size_t)c1.x * STRIDE + lo);
    gvec g2 = *(const gvec*)(src + (size_t)c2.x * STRIDE + lo);
    gvec g3 = *(const gvec*)(src + (size_t)c3.x * STRIDE + lo);
    float v0 = __int_as_float(c0.y), v1 = __int_as_float(c1.y);
    float v2 = __int_as_float(c2.y), v3 = __int_as_float(c3.y);
#pragma unroll
    for (int q = 0; q < NCH; ++q) {
      a[2 * q] = fmaf(v0, __builtin_bit_cast(float, g0[q] << 16), a[2 * q]);
      a[2 * q + 1] = fmaf(v0, __builtin_bit_cast(float, g0[q] & 0xffff0000u), a[2 * q + 1]);
      a[2 * q] = fmaf(v1, __builtin_bit_cast(float, g1[q] << 16), a[2 * q]);
      a[2 * q + 1] = fmaf(v1, __builtin_bit_cast(float, g1[q] & 0xffff0000u), a[2 * q + 1]);
      a[2 * q] = fmaf(v2, __builtin_bit_cast(float, g2[q] << 16), a[2 * q]);
      a[2 * q + 1] = fmaf(v2, __builtin_bit_cast(float, g2[q] & 0xffff0000u), a[2 * q + 1]);
      a[2 * q] = fmaf(v3, __builtin_bit_cast(float, g3[q] << 16), a[2 * q]);
      a[2 * q + 1] = fmaf(v3, __builtin_bit_cast(float, g3[q] & 0xffff0000u), a[2 * q + 1]);
    }
  }
  for (; i < e; ++i) {
    int2 cv = csr[i];
    float val = __int_as_float(cv.y);
    gvec g = *(const gvec*)(src + (size_t)cv.x * STRIDE + lo);
#pragma unroll
    for (int q = 0; q < NCH; ++q) {
      a[2 * q] = fmaf(val, __builtin_bit_cast(float, g[q] << 16), a[2 * q]);
      a[2 * q + 1] = fmaf(val, __builtin_bit_cast(float, g[q] & 0xffff0000u), a[2 * q + 1]);
    }
  }
  gvec o;
#pragma unroll
  for (int q = 0; q < NCH; ++q)
    o[q] = ((uint32_t)bf16_rne(a[2 * q + 1]) << 16) | (uint32_t)bf16_rne(a[2 * q]);
  *(gvec*)(dst + (size_t)r * STRIDE + lo) = o;
}

// ---- GEMM: out[i*NN+n][f] (+)= sum_k A[n][k] * wb[i*128+f][k] ----
template <int KTOT, int HOPW, int ACCUM>
__global__ __launch_bounds__(256) void k_gemm(
    const uint16_t* __restrict__ h0, const uint16_t* __restrict__ h1,
    const uint16_t* __restrict__ h2, const uint16_t* __restrict__ h3,
    const uint16_t* __restrict__ wb, float* __restrict__ out) {
  __shared__ __align__(16) uint16_t As[128 * 32]; // [row][k]
  __shared__ __align__(16) uint16_t Bs[128 * 32]; // [col][k]
  int t = threadIdx.x;
  int lane = t & 63, wid = t >> 6;
  int wm = wid >> 1, wn = wid & 1;
  int m0 = blockIdx.x * 128;
  int c0 = blockIdx.y * 128;
  int rl = lane & 15, kq = (lane >> 4) * 8;
  f32x4 acc[4][4] = {};
  for (int k0 = 0; k0 < KTOT; k0 += 32) {
    int hop = k0 / HOPW, kin = k0 % HOPW;
    const uint16_t* hm = hop == 0 ? h0 : hop == 1 ? h1 : hop == 2 ? h2 : h3;
#pragma unroll
    for (int rr = 0; rr < 2; ++rr) { // stage A tile: 512 chunks of 16B
      int c = rr * 256 + t;
      int row = c >> 2, kc = c & 3;
      int gr = m0 + row;
      gr = gr < NN ? gr : NN - 1; // clamp (dup row harmless, store guarded)
      GLDS16(hm + (size_t)gr * HOPW + kin + kc * 8, &As[c * 8]);
    }
#pragma unroll
    for (int rr = 0; rr < 2; ++rr) { // stage B tile
      int c = rr * 256 + t;
      int cc = c >> 2, kc = c & 3;
      GLDS16(wb + (size_t)(c0 + cc) * KTOT + k0 + kc * 8, &Bs[c * 8]);
    }
    __syncthreads();
    bf16x8 af[4], bq[4];
#pragma unroll
    for (int f = 0; f < 4; ++f)
      af[f] = *(const bf16x8*)(&As[(wm * 64 + f * 16 + rl) * 32 + kq]);
#pragma unroll
    for (int f = 0; f < 4; ++f)
      bq[f] = *(const bf16x8*)(&Bs[(wn * 64 + f * 16 + rl) * 32 + kq]);
#pragma unroll
    for (int fm = 0; fm < 4; ++fm)
#pragma unroll
      for (int fn = 0; fn < 4; ++fn)
        acc[fm][fn] = __builtin_amdgcn_mfma_f32_16x16x32_bf16(af[fm], bq[fn],
                                                              acc[fm][fn], 0, 0, 0);
    __syncthreads();
  }
  int iOut = blockIdx.y;
#pragma unroll
  for (int fm = 0; fm < 4; ++fm) {
#pragma unroll
    for (int r = 0; r < 4; ++r) {
      int rowg = m0 + wm * 64 + fm * 16 + (lane >> 4) * 4 + r;
      if (rowg >= NN) continue;
      float* op = out + ((size_t)iOut * NN + rowg) * D;
#pragma unroll
      for (int fn = 0; fn < 4; ++fn) {
        int colg = wn * 64 + fn * 16 + rl;
        if (ACCUM)
          op[colg] += acc[fm][fn][r];
        else
          op[colg] = acc[fm][fn][r];
      }
    }
  }
}

extern "C" void kernel_launch(void* const* d_in, const int* in_sizes, int n_in,
                              void* d_out, int out_size, void* d_ws, size_t ws_size,
                              hipStream_t stream) {
  (void)in_sizes; (void)n_in; (void)out_size;
  const float* x = (const float*)d_in[0];      // [2, N, 128]
  const int* ei = (const int*)d_in[1];         // [2, E]
  const float* W = (const float*)d_in[2];      // [2, 2, 128, 128]
  const float* params = (const float*)d_in[3]; // [2, 2, 4]
  float* out = (float*)d_out;                  // [2, N, 128]
  char* ws = (char*)d_ws;

  size_t off = 0;
  auto take = [&](size_t bytes) {
    char* p = ws + off;
    off = (off + bytes + 255) & ~(size_t)255;
    return p;
  };
  int* deg = (int*)take((size_t)NN * 4);
  float* dinv = (float*)take((size_t)NN * 4);
  int* rp = (int*)take((size_t)(NN + 1) * 4);
  int* cur = (int*)take((size_t)NN * 4);
  int* bsum = (int*)take(256 * 4);
  int* boff = (int*)take(256 * 4);
  int2* csr = (int2*)take((size_t)NE * 8);
  uint16_t* wb = (uint16_t*)take((size_t)256 * 1024 * 2); // 512 KB (both layouts fit)
  size_t fixed = off;

  hipMemsetAsync(deg, 0, (size_t)NN * 4, stream);
  k_deg<<<(NE + 255) / 256, 256, 0, stream>>>(ei, deg);
  k_dinv<<<(NN + 255) / 256, 256, 0, stream>>>(deg, dinv);
  k_bsum<<<SCAN_B, 256, 0, stream>>>(deg, bsum);
  k_bscan<<<1, 256, 0, stream>>>(bsum, boff);
  k_rpwrite<<<SCAN_B, 256, 0, stream>>>(deg, boff, rp, cur);
  k_scatter<<<(NE + 255) / 256, 256, 0, stream>>>(ei, ei + NE, dinv, cur, csr);

  size_t hopC = (size_t)NN * 256 * 2; // 25.6 MB per hop, combined channels
  size_t needC = fixed + 4 * hopC + 1024;

  if (ws_size >= needC) {
    // ---- fused-channel path: 3 spmm + 1 GEMM (K=1024) ----
    uint16_t* hop[4];
    for (int m = 0; m < 4; ++m) hop[m] = (uint16_t*)take(hopC);
    k_wbig_c<<<(256 * 1024 + 255) / 256, 256, 0, stream>>>(W, params, wb);
    k_x2h_c<<<(NN * 256 + 255) / 256, 256, 0, stream>>>(x, hop[0]);
    for (int m = 1; m <= KH; ++m)
      k_spmm<2><<<(NN + 3) / 4, 256, 0, stream>>>(rp, csr, hop[m - 1], hop[m]);
    dim3 grid((NN + 127) / 128, 2);
    k_gemm<1024, 256, 0><<<grid, 256, 0, stream>>>(hop[0], hop[1], hop[2], hop[3],
                                                   wb, out);
  } else {
    // ---- fallback: per-channel hops, 2 GEMMs ----
    size_t hopF = (size_t)NN * 128 * 2; // 12.8 MB
    uint16_t* hop[4];
    for (int m = 0; m < 4; ++m) hop[m] = (uint16_t*)take(hopF);
    k_wbig_f<<<(2 * 256 * 512 + 255) / 256, 256, 0, stream>>>(W, params, wb);
    for (int j = 0; j < 2; ++j) {
      k_x2h_f<<<(NN * D + 255) / 256, 256, 0, stream>>>(x + (size_t)j * NN * D, hop[0]);
      for (int m = 1; m <= KH; ++m)
        k_spmm<1><<<(NN + 3) / 4, 256, 0, stream>>>(rp, csr, hop[m - 1], hop[m]);
      dim3 grid((NN + 127) / 128, 2);
      if (j == 0)
        k_gemm<512, 128, 0><<<grid, 256, 0, stream>>>(hop[0], hop[1], hop[2], hop[3],
                                                      wb, out);
      else
        k_gemm<512, 128, 1><<<grid, 256, 0, stream>>>(hop[0], hop[1], hop[2], hop[3],
                                                      wb + 256 * 512, out);
    }
  }
}

// Round 4
// 416.992 us; speedup vs baseline: 2.0259x; 1.0121x over previous
//
#include <hip/hip_runtime.h>
#include <hip/hip_bf16.h>
#include <stdint.h>

#define NN 50000
#define NE 800000
#define D 128
#define KH 3
#define SCAN_B ((NN + 255) / 256) // 196

typedef __attribute__((ext_vector_type(8))) __bf16 bf16x8;
typedef __attribute__((ext_vector_type(4))) float f32x4;

__device__ __forceinline__ uint16_t bf16_rne(float f) {
  uint32_t u = __builtin_bit_cast(uint32_t, f);
  u = (u + 0x7fffu + ((u >> 16) & 1u)) >> 16;
  return (uint16_t)u;
}

// async global->LDS, 16B per lane; LDS dest is wave-uniform base + lane*16
#define GLDS16(gp, lp)                                                         \
  __builtin_amdgcn_global_load_lds(                                            \
      (__attribute__((address_space(1))) void*)(gp),                           \
      (__attribute__((address_space(3))) void*)(lp), 16, 0, 0)

__global__ void k_deg(const int* __restrict__ row, int* __restrict__ deg) {
  int e = blockIdx.x * 256 + threadIdx.x;
  if (e < NE) atomicAdd(&deg[row[e]], 1);
}

// fused: dinv + per-block degree sums
__global__ void k_dinv_bsum(const int* __restrict__ deg, float* __restrict__ dinv,
                            int* __restrict__ bsum) {
  __shared__ int s[256];
  int t = threadIdx.x;
  int i = blockIdx.x * 256 + t;
  int d = (i < NN) ? deg[i] : 0;
  if (i < NN) dinv[i] = (d > 0) ? rsqrtf((float)d) : 0.0f;
  s[t] = d;
  __syncthreads();
  for (int off = 128; off > 0; off >>= 1) {
    if (t < off) s[t] += s[t + off];
    __syncthreads();
  }
  if (t == 0) bsum[blockIdx.x] = s[0];
}

__global__ void k_bscan(const int* __restrict__ bsum, int* __restrict__ boff) {
  __shared__ int s[256];
  int t = threadIdx.x;
  int v = (t < SCAN_B) ? bsum[t] : 0;
  s[t] = v;
  __syncthreads();
  for (int off = 1; off < 256; off <<= 1) {
    int u = (t >= off) ? s[t - off] : 0;
    __syncthreads();
    s[t] += u;
    __syncthreads();
  }
  boff[t] = s[t] - v; // exclusive
}

__global__ void k_rpwrite(const int* __restrict__ deg, const int* __restrict__ boff,
                          int* __restrict__ rp, int* __restrict__ cur) {
  __shared__ int s[256];
  int t = threadIdx.x;
  int i = blockIdx.x * 256 + t;
  int v = (i < NN) ? deg[i] : 0;
  s[t] = v;
  __syncthreads();
  for (int off = 1; off < 256; off <<= 1) {
    int u = (t >= off) ? s[t - off] : 0;
    __syncthreads();
    s[t] += u;
    __syncthreads();
  }
  if (i < NN) {
    int r = boff[blockIdx.x] + s[t] - v;
    rp[i] = r;
    cur[i] = r;
  }
  if (i == 0) rp[NN] = NE;
}

__global__ void k_scatter(const int* __restrict__ row, const int* __restrict__ col,
                          const float* __restrict__ dinv, int* __restrict__ cur,
                          int2* __restrict__ csr) {
  int e = blockIdx.x * 256 + threadIdx.x;
  if (e < NE) {
    int r = row[e], c = col[e];
    int pos = atomicAdd(&cur[r], 1);
    csr[pos] = make_int2(c, __float_as_int(dinv[r] * dinv[c]));
  }
}

// fused hop0-convert + weight-prep (combined-channel layout).
// blocks [0,NN): dst[n][j*128+d] = bf16(x[j][n][d])
// blocks [NN, NN+1024): wb[c=256][k=1024], k->m=k>>8,j=(k>>7)&1,d=k&127; c->i=c>>7,f=c&127
__global__ void k_prep_c(const float* __restrict__ x, const float* __restrict__ W,
                         const float* __restrict__ params, uint16_t* __restrict__ dst,
                         uint16_t* __restrict__ wb) {
  int b = blockIdx.x, t = threadIdx.x;
  if (b < NN) {
    int idx = b * 256 + t;
    int n = idx >> 8, c = idx & 255, j = c >> 7, dd = c & 127;
    dst[idx] = bf16_rne(x[(size_t)j * NN * D + (size_t)n * D + dd]);
  } else {
    int idx = (b - NN) * 256 + t; // [0, 256*1024)
    int c = idx >> 10, k = idx & 1023;
    int i = c >> 7, f = c & 127, m = k >> 8, j = (k >> 7) & 1, dd = k & 127;
    float p = params[(i * 2 + j) * 4 + m];
    float w = W[((i * 2 + j) * 128 + dd) * 128 + f];
    wb[idx] = bf16_rne(p * w);
  }
}

// fallback variants
__global__ void k_wbig_f(const float* __restrict__ W, const float* __restrict__ params,
                         uint16_t* __restrict__ wb) {
  int idx = blockIdx.x * 256 + threadIdx.x;
  if (idx >= 2 * 256 * 512) return;
  int j = idx >> 17, c = (idx >> 9) & 255, k = idx & 511;
  int i = c >> 7, f = c & 127, m = k >> 7, dd = k & 127;
  float p = params[(i * 2 + j) * 4 + m];
  float w = W[((i * 2 + j) * 128 + dd) * 128 + f];
  wb[idx] = bf16_rne(p * w);
}

__global__ void k_x2h_f(const float* __restrict__ xj, uint16_t* __restrict__ dst) {
  int idx = blockIdx.x * 256 + threadIdx.x;
  if (idx < NN * D) dst[idx] = bf16_rne(xj[idx]);
}

// ---- SpMM: dst = A_norm @ src ----
// One wave per row; lane covers NCH dwords; csr extents scalarized; edge loop
// unrolled x8 -> 8 independent gathers in flight per lane.
template <int NCH>
__global__ void k_spmm(const int* __restrict__ rp, const int2* __restrict__ csr,
                       const uint16_t* __restrict__ src, uint16_t* __restrict__ dst) {
  constexpr int STRIDE = NCH * 128;
  typedef uint32_t gvec __attribute__((ext_vector_type(NCH)));
  const int lane = threadIdx.x & 63;
  const int wid = threadIdx.x >> 6;
  const int r = blockIdx.x * 4 + wid;
  if (r >= NN) return;
  const int s = __builtin_amdgcn_readfirstlane(rp[r]);
  const int e = __builtin_amdgcn_readfirstlane(rp[r + 1]);
  const int lo = lane * 2 * NCH;

  float a[2 * NCH] = {};
  int i = s;
  for (; i + 8 <= e; i += 8) {
    int2 cv[8];
    gvec g[8];
#pragma unroll
    for (int u = 0; u < 8; ++u) cv[u] = csr[i + u];
#pragma unroll
    for (int u = 0; u < 8; ++u)
      g[u] = *(const gvec*)(src + (size_t)cv[u].x * STRIDE + lo);
#pragma unroll
    for (int u = 0; u < 8; ++u) {
      float v = __int_as_float(cv[u].y);
#pragma unroll
      for (int q = 0; q < NCH; ++q) {
        a[2 * q] = fmaf(v, __builtin_bit_cast(float, g[u][q] << 16), a[2 * q]);
        a[2 * q + 1] =
            fmaf(v, __builtin_bit_cast(float, g[u][q] & 0xffff0000u), a[2 * q + 1]);
      }
    }
  }
  for (; i + 4 <= e; i += 4) {
    int2 cv[4];
    gvec g[4];
#pragma unroll
    for (int u = 0; u < 4; ++u) cv[u] = csr[i + u];
#pragma unroll
    for (int u = 0; u < 4; ++u)
      g[u] = *(const gvec*)(src + (size_t)cv[u].x * STRIDE + lo);
#pragma unroll
    for (int u = 0; u < 4; ++u) {
      float v = __int_as_float(cv[u].y);
#pragma unroll
      for (int q = 0; q < NCH; ++q) {
        a[2 * q] = fmaf(v, __builtin_bit_cast(float, g[u][q] << 16), a[2 * q]);
        a[2 * q + 1] =
            fmaf(v, __builtin_bit_cast(float, g[u][q] & 0xffff0000u), a[2 * q + 1]);
      }
    }
  }
  for (; i < e; ++i) {
    int2 cv = csr[i];
    float v = __int_as_float(cv.y);
    gvec g = *(const gvec*)(src + (size_t)cv.x * STRIDE + lo);
#pragma unroll
    for (int q = 0; q < NCH; ++q) {
      a[2 * q] = fmaf(v, __builtin_bit_cast(float, g[q] << 16), a[2 * q]);
      a[2 * q + 1] = fmaf(v, __builtin_bit_cast(float, g[q] & 0xffff0000u), a[2 * q + 1]);
    }
  }
  gvec o;
#pragma unroll
  for (int q = 0; q < NCH; ++q)
    o[q] = ((uint32_t)bf16_rne(a[2 * q + 1]) << 16) | (uint32_t)bf16_rne(a[2 * q]);
  *(gvec*)(dst + (size_t)r * STRIDE + lo) = o;
}

// ---- GEMM: out[i*NN+n][f] (+)= sum_k A[n][k] * wb[i*128+f][k] ----
// LDS XOR-swizzle: slot (row,kc) holds global chunk kc^(row&3); since the
// global_load_lds dest is lane-contiguous, the swizzle is applied on the
// GLOBAL source address at store and on the chunk index at read.
// Post-swizzle ds_read_b128 conflict degree: 2-way (free, m136).
template <int KTOT, int HOPW, int ACCUM>
__global__ __launch_bounds__(256) void k_gemm(
    const uint16_t* __restrict__ h0, const uint16_t* __restrict__ h1,
    const uint16_t* __restrict__ h2, const uint16_t* __restrict__ h3,
    const uint16_t* __restrict__ wb, float* __restrict__ out) {
  __shared__ __align__(16) uint16_t As[128 * 32]; // slot[row][kc] 16B chunks
  __shared__ __align__(16) uint16_t Bs[128 * 32];
  const uint16_t* hops[4] = {h0, h1, h2, h3};
  int t = threadIdx.x;
  int lane = t & 63, wid = t >> 6;
  int wm = wid >> 1, wn = wid & 1;
  int m0 = blockIdx.x * 128;
  int c0 = blockIdx.y * 128;
  int rl = lane & 15, q = lane >> 4;
  f32x4 acc[4][4] = {};
#pragma unroll
  for (int hop = 0; hop < KTOT / HOPW; ++hop) {
    const uint16_t* hm = hops[hop];
    for (int kin = 0; kin < HOPW; kin += 32) {
      int k0 = hop * HOPW + kin;
#pragma unroll
      for (int rr = 0; rr < 2; ++rr) { // stage A tile: 512 chunks of 16B
        int c = rr * 256 + t;
        int row = c >> 2, kcL = c & 3;
        int kcG = kcL ^ (row & 3); // swizzle on global source
        int gr = m0 + row;
        gr = gr < NN ? gr : NN - 1; // clamp (dup row harmless, store guarded)
        GLDS16(hm + (size_t)gr * HOPW + kin + kcG * 8, &As[c * 8]);
      }
#pragma unroll
      for (int rr = 0; rr < 2; ++rr) { // stage B tile
        int c = rr * 256 + t;
        int cc = c >> 2, kcL = c & 3;
        int kcG = kcL ^ (cc & 3);
        GLDS16(wb + (size_t)(c0 + cc) * KTOT + k0 + kcG * 8, &Bs[c * 8]);
      }
      __syncthreads();
      bf16x8 af[4], bq[4];
#pragma unroll
      for (int f = 0; f < 4; ++f) {
        int row = wm * 64 + f * 16 + rl;
        int kc = q ^ (rl & 3);
        af[f] = *(const bf16x8*)(&As[row * 32 + kc * 8]);
      }
#pragma unroll
      for (int f = 0; f < 4; ++f) {
        int row = wn * 64 + f * 16 + rl;
        int kc = q ^ (rl & 3);
        bq[f] = *(const bf16x8*)(&Bs[row * 32 + kc * 8]);
      }
#pragma unroll
      for (int fm = 0; fm < 4; ++fm)
#pragma unroll
        for (int fn = 0; fn < 4; ++fn)
          acc[fm][fn] = __builtin_amdgcn_mfma_f32_16x16x32_bf16(af[fm], bq[fn],
                                                                acc[fm][fn], 0, 0, 0);
      __syncthreads();
    }
  }
  int iOut = blockIdx.y;
#pragma unroll
  for (int fm = 0; fm < 4; ++fm) {
#pragma unroll
    for (int r = 0; r < 4; ++r) {
      int rowg = m0 + wm * 64 + fm * 16 + q * 4 + r;
      if (rowg >= NN) continue;
      float* op = out + ((size_t)iOut * NN + rowg) * D;
#pragma unroll
      for (int fn = 0; fn < 4; ++fn) {
        int colg = wn * 64 + fn * 16 + rl;
        if (ACCUM)
          op[colg] += acc[fm][fn][r];
        else
          op[colg] = acc[fm][fn][r];
      }
    }
  }
}

extern "C" void kernel_launch(void* const* d_in, const int* in_sizes, int n_in,
                              void* d_out, int out_size, void* d_ws, size_t ws_size,
                              hipStream_t stream) {
  (void)in_sizes; (void)n_in; (void)out_size;
  const float* x = (const float*)d_in[0];      // [2, N, 128]
  const int* ei = (const int*)d_in[1];         // [2, E]
  const float* W = (const float*)d_in[2];      // [2, 2, 128, 128]
  const float* params = (const float*)d_in[3]; // [2, 2, 4]
  float* out = (float*)d_out;                  // [2, N, 128]
  char* ws = (char*)d_ws;

  size_t off = 0;
  auto take = [&](size_t bytes) {
    char* p = ws + off;
    off = (off + bytes + 255) & ~(size_t)255;
    return p;
  };
  int* deg = (int*)take((size_t)NN * 4);
  float* dinv = (float*)take((size_t)NN * 4);
  int* rp = (int*)take((size_t)(NN + 1) * 4);
  int* cur = (int*)take((size_t)NN * 4);
  int* bsum = (int*)take(256 * 4);
  int* boff = (int*)take(256 * 4);
  int2* csr = (int2*)take((size_t)NE * 8);
  uint16_t* wb = (uint16_t*)take((size_t)256 * 1024 * 2); // 512 KB
  size_t fixed = off;

  hipMemsetAsync(deg, 0, (size_t)NN * 4, stream);
  k_deg<<<(NE + 255) / 256, 256, 0, stream>>>(ei, deg);
  k_dinv_bsum<<<SCAN_B, 256, 0, stream>>>(deg, dinv, bsum);
  k_bscan<<<1, 256, 0, stream>>>(bsum, boff);
  k_rpwrite<<<SCAN_B, 256, 0, stream>>>(deg, boff, rp, cur);
  k_scatter<<<(NE + 255) / 256, 256, 0, stream>>>(ei, ei + NE, dinv, cur, csr);

  size_t hopC = (size_t)NN * 256 * 2; // 25.6 MB per hop, combined channels
  size_t needC = fixed + 4 * hopC + 1024;

  if (ws_size >= needC) {
    // ---- fused-channel path: 3 spmm + 1 GEMM (K=1024) ----
    uint16_t* hop[4];
    for (int m = 0; m < 4; ++m) hop[m] = (uint16_t*)take(hopC);
    k_prep_c<<<NN + 1024, 256, 0, stream>>>(x, W, params, hop[0], wb);
    for (int m = 1; m <= KH; ++m)
      k_spmm<2><<<(NN + 3) / 4, 256, 0, stream>>>(rp, csr, hop[m - 1], hop[m]);
    dim3 grid((NN + 127) / 128, 2);
    k_gemm<1024, 256, 0><<<grid, 256, 0, stream>>>(hop[0], hop[1], hop[2], hop[3],
                                                   wb, out);
  } else {
    // ---- fallback: per-channel hops, 2 GEMMs ----
    size_t hopF = (size_t)NN * 128 * 2;
    uint16_t* hop[4];
    for (int m = 0; m < 4; ++m) hop[m] = (uint16_t*)take(hopF);
    k_wbig_f<<<(2 * 256 * 512 + 255) / 256, 256, 0, stream>>>(W, params, wb);
    for (int j = 0; j < 2; ++j) {
      k_x2h_f<<<(NN * D + 255) / 256, 256, 0, stream>>>(x + (size_t)j * NN * D, hop[0]);
      for (int m = 1; m <= KH; ++m)
        k_spmm<1><<<(NN + 3) / 4, 256, 0, stream>>>(rp, csr, hop[m - 1], hop[m]);
      dim3 grid((NN + 127) / 128, 2);
      if (j == 0)
        k_gemm<512, 128, 0><<<grid, 256, 0, stream>>>(hop[0], hop[1], hop[2], hop[3],
                                                      wb, out);
      else
        k_gemm<512, 128, 1><<<grid, 256, 0, stream>>>(hop[0], hop[1], hop[2], hop[3],
                                                      wb + 256 * 512, out);
    }
  }
}

// Round 5
// 411.099 us; speedup vs baseline: 2.0550x; 1.0143x over previous
//
#include <hip/hip_runtime.h>
#include <hip/hip_bf16.h>
#include <stdint.h>

#define NN 50000
#define NE 800000
#define D 128
#define KH 3
#define SCAN_B ((NN + 255) / 256) // 196

typedef __attribute__((ext_vector_type(8))) __bf16 bf16x8;
typedef __attribute__((ext_vector_type(4))) float f32x4;

__device__ __forceinline__ uint16_t bf16_rne(float f) {
  uint32_t u = __builtin_bit_cast(uint32_t, f);
  u = (u + 0x7fffu + ((u >> 16) & 1u)) >> 16;
  return (uint16_t)u;
}
__device__ __forceinline__ uint32_t bf16_pack(float lo, float hi) {
  return ((uint32_t)bf16_rne(hi) << 16) | (uint32_t)bf16_rne(lo);
}

// async global->LDS, 16B per lane; LDS dest is wave-uniform base + lane*16
#define GLDS16(gp, lp)                                                         \
  __builtin_amdgcn_global_load_lds(                                            \
      (__attribute__((address_space(1))) void*)(gp),                           \
      (__attribute__((address_space(3))) void*)(lp), 16, 0, 0)

__global__ void k_deg(const int* __restrict__ row, int* __restrict__ deg) {
  int e = blockIdx.x * 256 + threadIdx.x;
  if (e < NE) atomicAdd(&deg[row[e]], 1);
}

// fused: dinv + per-block degree sums
__global__ void k_dinv_bsum(const int* __restrict__ deg, float* __restrict__ dinv,
                            int* __restrict__ bsum) {
  __shared__ int s[256];
  int t = threadIdx.x;
  int i = blockIdx.x * 256 + t;
  int d = (i < NN) ? deg[i] : 0;
  if (i < NN) dinv[i] = (d > 0) ? rsqrtf((float)d) : 0.0f;
  s[t] = d;
  __syncthreads();
  for (int off = 128; off > 0; off >>= 1) {
    if (t < off) s[t] += s[t + off];
    __syncthreads();
  }
  if (t == 0) bsum[blockIdx.x] = s[0];
}

// rp/cur writer; block offset computed in-block from bsum (k_bscan folded in)
__global__ void k_rpwrite(const int* __restrict__ deg, const int* __restrict__ bsum,
                          int* __restrict__ rp, int* __restrict__ cur) {
  __shared__ int s[256];
  __shared__ int sboff;
  int t = threadIdx.x;
  int b = blockIdx.x;
  int pv = (t < b) ? bsum[t] : 0; // b < SCAN_B <= 256
  s[t] = pv;
  __syncthreads();
  for (int off = 128; off > 0; off >>= 1) {
    if (t < off) s[t] += s[t + off];
    __syncthreads();
  }
  if (t == 0) sboff = s[0];
  __syncthreads();
  int i = b * 256 + t;
  int v = (i < NN) ? deg[i] : 0;
  s[t] = v;
  __syncthreads();
  for (int off = 1; off < 256; off <<= 1) {
    int u = (t >= off) ? s[t - off] : 0;
    __syncthreads();
    s[t] += u;
    __syncthreads();
  }
  if (i < NN) {
    int r = sboff + s[t] - v;
    rp[i] = r;
    cur[i] = r;
  }
  if (i == 0) rp[NN] = NE;
}

__global__ void k_scatter(const int* __restrict__ row, const int* __restrict__ col,
                          const float* __restrict__ dinv, int* __restrict__ cur,
                          int2* __restrict__ csr) {
  int e = blockIdx.x * 256 + threadIdx.x;
  if (e < NE) {
    int r = row[e], c = col[e];
    int pos = atomicAdd(&cur[r], 1);
    csr[pos] = make_int2(c, __float_as_int(dinv[r] * dinv[c]));
  }
}

// fused hop0-convert (8 elems/thread) + weight-prep.
// blocks [0,6250): dst[n][j*128+d] = bf16(x[j][n][d]), 8 bf16 per thread
// blocks [6250, 6250+1024): wb[c=256][k=1024]
#define XB 6250
__global__ void k_prep_c(const float* __restrict__ x, const float* __restrict__ W,
                         const float* __restrict__ params, uint16_t* __restrict__ dst,
                         uint16_t* __restrict__ wb) {
  int b = blockIdx.x, t = threadIdx.x;
  if (b < XB) {
    int base = (b * 256 + t) * 8; // elem idx in dst
    int n = base >> 8, c0 = base & 255;
    int j = c0 >> 7, dd = c0 & 127;
    const float* xp = x + (size_t)j * NN * D + (size_t)n * D + dd;
    float4 f0 = *(const float4*)xp;
    float4 f1 = *(const float4*)(xp + 4);
    uint4 o;
    o.x = bf16_pack(f0.x, f0.y);
    o.y = bf16_pack(f0.z, f0.w);
    o.z = bf16_pack(f1.x, f1.y);
    o.w = bf16_pack(f1.z, f1.w);
    *(uint4*)(dst + base) = o;
  } else {
    int idx = (b - XB) * 256 + t; // [0, 256*1024)
    int c = idx >> 10, k = idx & 1023;
    int i = c >> 7, f = c & 127, m = k >> 8, j = (k >> 7) & 1, dd = k & 127;
    float p = params[(i * 2 + j) * 4 + m];
    float w = W[((i * 2 + j) * 128 + dd) * 128 + f];
    wb[idx] = bf16_rne(p * w);
  }
}

// fallback variants
__global__ void k_wbig_f(const float* __restrict__ W, const float* __restrict__ params,
                         uint16_t* __restrict__ wb) {
  int idx = blockIdx.x * 256 + threadIdx.x;
  if (idx >= 2 * 256 * 512) return;
  int j = idx >> 17, c = (idx >> 9) & 255, k = idx & 511;
  int i = c >> 7, f = c & 127, m = k >> 7, dd = k & 127;
  float p = params[(i * 2 + j) * 4 + m];
  float w = W[((i * 2 + j) * 128 + dd) * 128 + f];
  wb[idx] = bf16_rne(p * w);
}

__global__ void k_x2h_f(const float* __restrict__ xj, uint16_t* __restrict__ dst) {
  int idx = blockIdx.x * 256 + threadIdx.x;
  if (idx < NN * D) dst[idx] = bf16_rne(xj[idx]);
}

// ---- SpMM: dst = A_norm @ src ----
// One wave per row; HALF-WAVE per edge: 32 lanes cover the row (NCH*8 bytes
// per lane, dwordx{2*NCH}), the two halves process alternating edges ->
// half the gather instrs per edge, 16 edges in flight per batch.
// Final __shfl_xor(32) combines the two halves' partial sums.
template <int NCH>
__global__ void k_spmm(const int* __restrict__ rp, const int2* __restrict__ csr,
                       const uint16_t* __restrict__ src, uint16_t* __restrict__ dst) {
  constexpr int STRIDE = NCH * 128; // elems per row
  constexpr int NDW = NCH * 2;      // dwords per lane
  typedef uint32_t gvec __attribute__((ext_vector_type(NDW)));
  const int lane = threadIdx.x & 63;
  const int wid = threadIdx.x >> 6;
  const int r = blockIdx.x * 4 + wid;
  if (r >= NN) return;
  const int s = __builtin_amdgcn_readfirstlane(rp[r]);
  const int e = __builtin_amdgcn_readfirstlane(rp[r + 1]);
  const int half = lane >> 5;
  const int lo = (lane & 31) * 2 * NDW; // elem offset within row

  float a[2 * NDW] = {};
  int i = s;
  for (; i + 16 <= e; i += 16) {
    int2 cv[8];
    gvec g[8];
#pragma unroll
    for (int u = 0; u < 8; ++u) cv[u] = csr[i + 2 * u + half];
#pragma unroll
    for (int u = 0; u < 8; ++u)
      g[u] = *(const gvec*)(src + (size_t)cv[u].x * STRIDE + lo);
#pragma unroll
    for (int u = 0; u < 8; ++u) {
      float v = __int_as_float(cv[u].y);
#pragma unroll
      for (int q = 0; q < NDW; ++q) {
        a[2 * q] = fmaf(v, __builtin_bit_cast(float, g[u][q] << 16), a[2 * q]);
        a[2 * q + 1] =
            fmaf(v, __builtin_bit_cast(float, g[u][q] & 0xffff0000u), a[2 * q + 1]);
      }
    }
  }
  for (; i + 2 <= e; i += 2) {
    int2 cv = csr[i + half];
    float v = __int_as_float(cv.y);
    gvec g = *(const gvec*)(src + (size_t)cv.x * STRIDE + lo);
#pragma unroll
    for (int q = 0; q < NDW; ++q) {
      a[2 * q] = fmaf(v, __builtin_bit_cast(float, g[q] << 16), a[2 * q]);
      a[2 * q + 1] = fmaf(v, __builtin_bit_cast(float, g[q] & 0xffff0000u), a[2 * q + 1]);
    }
  }
  if (i < e && half == 0) { // odd tail edge: half-0 lanes only
    int2 cv = csr[i];
    float v = __int_as_float(cv.y);
    gvec g = *(const gvec*)(src + (size_t)cv.x * STRIDE + lo);
#pragma unroll
    for (int q = 0; q < NDW; ++q) {
      a[2 * q] = fmaf(v, __builtin_bit_cast(float, g[q] << 16), a[2 * q]);
      a[2 * q + 1] = fmaf(v, __builtin_bit_cast(float, g[q] & 0xffff0000u), a[2 * q + 1]);
    }
  }
  // combine the two half-wave partial sums
#pragma unroll
  for (int q = 0; q < 2 * NDW; ++q) a[q] += __shfl_xor(a[q], 32);
  if (half == 0) {
    gvec o;
#pragma unroll
    for (int q = 0; q < NDW; ++q) o[q] = bf16_pack(a[2 * q], a[2 * q + 1]);
    *(gvec*)(dst + (size_t)r * STRIDE + lo) = o;
  }
}

// ---- GEMM: out[i*NN+n][f] (+)= sum_k A[n][k] * wb[i*128+f][k] ----
// BK=64: 16KB As + 16KB Bs, 16 barriers (vs 32), 8 GLDS16/thread in flight.
// Row stride 128B aliases banks every row -> XOR-swizzle 16B-chunk index by
// (row&7), applied on the GLOBAL source (LDS dest of global_load_lds is
// lane-fixed). Post-swizzle quad reads are 2-way = free (m136).
template <int KTOT, int HOPW, int ACCUM>
__global__ __launch_bounds__(256) void k_gemm(
    const uint16_t* __restrict__ h0, const uint16_t* __restrict__ h1,
    const uint16_t* __restrict__ h2, const uint16_t* __restrict__ h3,
    const uint16_t* __restrict__ wb, float* __restrict__ out) {
  __shared__ __align__(16) uint16_t As[128 * 64];
  __shared__ __align__(16) uint16_t Bs[128 * 64];
  const uint16_t* hops[4] = {h0, h1, h2, h3};
  int t = threadIdx.x;
  int lane = t & 63, wid = t >> 6;
  int wm = wid >> 1, wn = wid & 1;
  int m0 = blockIdx.x * 128;
  int c0 = blockIdx.y * 128;
  int rl = lane & 15, q = lane >> 4;
  f32x4 acc[4][4] = {};
#pragma unroll
  for (int hop = 0; hop < KTOT / HOPW; ++hop) {
    const uint16_t* hm = hops[hop];
#pragma unroll
    for (int kin = 0; kin < HOPW; kin += 64) {
      int k0 = hop * HOPW + kin;
#pragma unroll
      for (int rr = 0; rr < 4; ++rr) { // stage A: 1024 chunks of 16B
        int c = rr * 256 + t;
        int row = c >> 3, kcL = c & 7;
        int kcG = kcL ^ (row & 7); // swizzle on global source
        int gr = m0 + row;
        gr = gr < NN ? gr : NN - 1; // clamp (dup row harmless, store guarded)
        GLDS16(hm + (size_t)gr * HOPW + kin + kcG * 8, &As[c * 8]);
      }
#pragma unroll
      for (int rr = 0; rr < 4; ++rr) { // stage B
        int c = rr * 256 + t;
        int cc = c >> 3, kcL = c & 7;
        int kcG = kcL ^ (cc & 7);
        GLDS16(wb + (size_t)(c0 + cc) * KTOT + k0 + kcG * 8, &Bs[c * 8]);
      }
      __syncthreads();
#pragma unroll
      for (int kq2 = 0; kq2 < 2; ++kq2) { // two K=32 halves of BK=64
        int w = kq2 * 4 + q;              // wanted 16B chunk 0..7
        bf16x8 af[4], bq[4];
#pragma unroll
        for (int f = 0; f < 4; ++f) {
          int row = wm * 64 + f * 16 + rl;
          af[f] = *(const bf16x8*)(&As[row * 64 + (w ^ (row & 7)) * 8]);
          int col = wn * 64 + f * 16 + rl;
          bq[f] = *(const bf16x8*)(&Bs[col * 64 + (w ^ (col & 7)) * 8]);
        }
#pragma unroll
        for (int fm = 0; fm < 4; ++fm)
#pragma unroll
          for (int fn = 0; fn < 4; ++fn)
            acc[fm][fn] = __builtin_amdgcn_mfma_f32_16x16x32_bf16(af[fm], bq[fn],
                                                                  acc[fm][fn], 0, 0, 0);
      }
      __syncthreads();
    }
  }
  int iOut = blockIdx.y;
#pragma unroll
  for (int fm = 0; fm < 4; ++fm) {
#pragma unroll
    for (int r = 0; r < 4; ++r) {
      int rowg = m0 + wm * 64 + fm * 16 + q * 4 + r;
      if (rowg >= NN) continue;
      float* op = out + ((size_t)iOut * NN + rowg) * D;
#pragma unroll
      for (int fn = 0; fn < 4; ++fn) {
        int colg = wn * 64 + fn * 16 + rl;
        if (ACCUM)
          op[colg] += acc[fm][fn][r];
        else
          op[colg] = acc[fm][fn][r];
      }
    }
  }
}

extern "C" void kernel_launch(void* const* d_in, const int* in_sizes, int n_in,
                              void* d_out, int out_size, void* d_ws, size_t ws_size,
                              hipStream_t stream) {
  (void)in_sizes; (void)n_in; (void)out_size;
  const float* x = (const float*)d_in[0];      // [2, N, 128]
  const int* ei = (const int*)d_in[1];         // [2, E]
  const float* W = (const float*)d_in[2];      // [2, 2, 128, 128]
  const float* params = (const float*)d_in[3]; // [2, 2, 4]
  float* out = (float*)d_out;                  // [2, N, 128]
  char* ws = (char*)d_ws;

  size_t off = 0;
  auto take = [&](size_t bytes) {
    char* p = ws + off;
    off = (off + bytes + 255) & ~(size_t)255;
    return p;
  };
  int* deg = (int*)take((size_t)NN * 4);
  float* dinv = (float*)take((size_t)NN * 4);
  int* rp = (int*)take((size_t)(NN + 1) * 4);
  int* cur = (int*)take((size_t)NN * 4);
  int* bsum = (int*)take(256 * 4);
  int2* csr = (int2*)take((size_t)NE * 8);
  uint16_t* wb = (uint16_t*)take((size_t)256 * 1024 * 2); // 512 KB
  size_t fixed = off;

  hipMemsetAsync(deg, 0, (size_t)NN * 4, stream);
  k_deg<<<(NE + 255) / 256, 256, 0, stream>>>(ei, deg);
  k_dinv_bsum<<<SCAN_B, 256, 0, stream>>>(deg, dinv, bsum);
  k_rpwrite<<<SCAN_B, 256, 0, stream>>>(deg, bsum, rp, cur);
  k_scatter<<<(NE + 255) / 256, 256, 0, stream>>>(ei, ei + NE, dinv, cur, csr);

  size_t hopC = (size_t)NN * 256 * 2; // 25.6 MB per hop, combined channels
  size_t needC = fixed + 4 * hopC + 1024;

  if (ws_size >= needC) {
    // ---- fused-channel path: 3 spmm + 1 GEMM (K=1024) ----
    uint16_t* hop[4];
    for (int m = 0; m < 4; ++m) hop[m] = (uint16_t*)take(hopC);
    k_prep_c<<<XB + 1024, 256, 0, stream>>>(x, W, params, hop[0], wb);
    for (int m = 1; m <= KH; ++m)
      k_spmm<2><<<(NN + 3) / 4, 256, 0, stream>>>(rp, csr, hop[m - 1], hop[m]);
    dim3 grid((NN + 127) / 128, 2);
    k_gemm<1024, 256, 0><<<grid, 256, 0, stream>>>(hop[0], hop[1], hop[2], hop[3],
                                                   wb, out);
  } else {
    // ---- fallback: per-channel hops, 2 GEMMs ----
    size_t hopF = (size_t)NN * 128 * 2;
    uint16_t* hop[4];
    for (int m = 0; m < 4; ++m) hop[m] = (uint16_t*)take(hopF);
    k_wbig_f<<<(2 * 256 * 512 + 255) / 256, 256, 0, stream>>>(W, params, wb);
    for (int j = 0; j < 2; ++j) {
      k_x2h_f<<<(NN * D + 255) / 256, 256, 0, stream>>>(x + (size_t)j * NN * D, hop[0]);
      for (int m = 1; m <= KH; ++m)
        k_spmm<1><<<(NN + 3) / 4, 256, 0, stream>>>(rp, csr, hop[m - 1], hop[m]);
      dim3 grid((NN + 127) / 128, 2);
      if (j == 0)
        k_gemm<512, 128, 0><<<grid, 256, 0, stream>>>(hop[0], hop[1], hop[2], hop[3],
                                                      wb, out);
      else
        k_gemm<512, 128, 1><<<grid, 256, 0, stream>>>(hop[0], hop[1], hop[2], hop[3],
                                                      wb + 256 * 512, out);
    }
  }
}

// Round 6
// 392.081 us; speedup vs baseline: 2.1547x; 1.0485x over previous
//
#include <hip/hip_runtime.h>
#include <hip/hip_bf16.h>
#include <stdint.h>

#define NN 50000
#define NE 800000
#define D 128
#define KH 3
#define SCAN_B ((NN + 255) / 256) // 196

typedef __attribute__((ext_vector_type(8))) __bf16 bf16x8;
typedef __attribute__((ext_vector_type(4))) float f32x4;

__device__ __forceinline__ uint16_t bf16_rne(float f) {
  uint32_t u = __builtin_bit_cast(uint32_t, f);
  u = (u + 0x7fffu + ((u >> 16) & 1u)) >> 16;
  return (uint16_t)u;
}
__device__ __forceinline__ uint32_t bf16_pack(float lo, float hi) {
  return ((uint32_t)bf16_rne(hi) << 16) | (uint32_t)bf16_rne(lo);
}

// async global->LDS, 16B per lane; LDS dest is wave-uniform base + lane*16
#define GLDS16(gp, lp)                                                         \
  __builtin_amdgcn_global_load_lds(                                            \
      (__attribute__((address_space(1))) void*)(gp),                           \
      (__attribute__((address_space(3))) void*)(lp), 16, 0, 0)

__global__ void k_deg(const int* __restrict__ row, int* __restrict__ deg) {
  int e = blockIdx.x * 256 + threadIdx.x;
  if (e < NE) atomicAdd(&deg[row[e]], 1);
}

// fused: dinv + per-block degree sums
__global__ void k_dinv_bsum(const int* __restrict__ deg, float* __restrict__ dinv,
                            int* __restrict__ bsum) {
  __shared__ int s[256];
  int t = threadIdx.x;
  int i = blockIdx.x * 256 + t;
  int d = (i < NN) ? deg[i] : 0;
  if (i < NN) dinv[i] = (d > 0) ? rsqrtf((float)d) : 0.0f;
  s[t] = d;
  __syncthreads();
  for (int off = 128; off > 0; off >>= 1) {
    if (t < off) s[t] += s[t + off];
    __syncthreads();
  }
  if (t == 0) bsum[blockIdx.x] = s[0];
}

// rp/cur writer; block offset computed in-block from bsum
__global__ void k_rpwrite(const int* __restrict__ deg, const int* __restrict__ bsum,
                          int* __restrict__ rp, int* __restrict__ cur) {
  __shared__ int s[256];
  __shared__ int sboff;
  int t = threadIdx.x;
  int b = blockIdx.x;
  int pv = (t < b) ? bsum[t] : 0; // b < SCAN_B <= 256
  s[t] = pv;
  __syncthreads();
  for (int off = 128; off > 0; off >>= 1) {
    if (t < off) s[t] += s[t + off];
    __syncthreads();
  }
  if (t == 0) sboff = s[0];
  __syncthreads();
  int i = b * 256 + t;
  int v = (i < NN) ? deg[i] : 0;
  s[t] = v;
  __syncthreads();
  for (int off = 1; off < 256; off <<= 1) {
    int u = (t >= off) ? s[t - off] : 0;
    __syncthreads();
    s[t] += u;
    __syncthreads();
  }
  if (i < NN) {
    int r = sboff + s[t] - v;
    rp[i] = r;
    cur[i] = r;
  }
  if (i == 0) rp[NN] = NE;
}

__global__ void k_scatter(const int* __restrict__ row, const int* __restrict__ col,
                          const float* __restrict__ dinv, int* __restrict__ cur,
                          int2* __restrict__ csr) {
  int e = blockIdx.x * 256 + threadIdx.x;
  if (e < NE) {
    int r = row[e], c = col[e];
    int pos = atomicAdd(&cur[r], 1);
    csr[pos] = make_int2(c, __float_as_int(dinv[r] * dinv[c]));
  }
}

// fused hop0-convert (8 elems/thread) + weight-prep.
#define XB 6250
__global__ void k_prep_c(const float* __restrict__ x, const float* __restrict__ W,
                         const float* __restrict__ params, uint16_t* __restrict__ dst,
                         uint16_t* __restrict__ wb) {
  int b = blockIdx.x, t = threadIdx.x;
  if (b < XB) {
    int base = (b * 256 + t) * 8; // elem idx in dst
    int n = base >> 8, c0 = base & 255;
    int j = c0 >> 7, dd = c0 & 127;
    const float* xp = x + (size_t)j * NN * D + (size_t)n * D + dd;
    float4 f0 = *(const float4*)xp;
    float4 f1 = *(const float4*)(xp + 4);
    uint4 o;
    o.x = bf16_pack(f0.x, f0.y);
    o.y = bf16_pack(f0.z, f0.w);
    o.z = bf16_pack(f1.x, f1.y);
    o.w = bf16_pack(f1.z, f1.w);
    *(uint4*)(dst + base) = o;
  } else {
    int idx = (b - XB) * 256 + t; // [0, 256*1024)
    int c = idx >> 10, k = idx & 1023;
    int i = c >> 7, f = c & 127, m = k >> 8, j = (k >> 7) & 1, dd = k & 127;
    float p = params[(i * 2 + j) * 4 + m];
    float w = W[((i * 2 + j) * 128 + dd) * 128 + f];
    wb[idx] = bf16_rne(p * w);
  }
}

// fallback variants
__global__ void k_wbig_f(const float* __restrict__ W, const float* __restrict__ params,
                         uint16_t* __restrict__ wb) {
  int idx = blockIdx.x * 256 + threadIdx.x;
  if (idx >= 2 * 256 * 512) return;
  int j = idx >> 17, c = (idx >> 9) & 255, k = idx & 511;
  int i = c >> 7, f = c & 127, m = k >> 7, dd = k & 127;
  float p = params[(i * 2 + j) * 4 + m];
  float w = W[((i * 2 + j) * 128 + dd) * 128 + f];
  wb[idx] = bf16_rne(p * w);
}

__global__ void k_x2h_f(const float* __restrict__ xj, uint16_t* __restrict__ dst) {
  int idx = blockIdx.x * 256 + threadIdx.x;
  if (idx < NN * D) dst[idx] = bf16_rne(xj[idx]);
}

// ---- SpMM: dst = A_norm @ src ----
// One wave per row, full wave per edge (dwordx{NCH}/lane). UNIFORM clamped
// 8-batches: every iteration issues 8 independent gathers; out-of-range
// slots clamp to edge e-1 (cache-hot dup) with val=0. No narrow tail loops
// (round-5 lesson: deg~16 made 2-edge tail loops serialize ~7 round-trips).
template <int NCH>
__global__ void k_spmm(const int* __restrict__ rp, const int2* __restrict__ csr,
                       const uint16_t* __restrict__ src, uint16_t* __restrict__ dst) {
  constexpr int STRIDE = NCH * 128;
  typedef uint32_t gvec __attribute__((ext_vector_type(NCH)));
  const int lane = threadIdx.x & 63;
  const int wid = threadIdx.x >> 6;
  const int r = blockIdx.x * 4 + wid;
  if (r >= NN) return;
  const int s = __builtin_amdgcn_readfirstlane(rp[r]);
  const int e = __builtin_amdgcn_readfirstlane(rp[r + 1]);
  const int lo = lane * 2 * NCH;

  float a[2 * NCH] = {};
  for (int i = s; i < e; i += 8) {
    int2 cv[8];
    gvec g[8];
#pragma unroll
    for (int u = 0; u < 8; ++u) {
      int idx = i + u;
      bool ok = idx < e;
      cv[u] = csr[ok ? idx : e - 1];
      if (!ok) cv[u].y = 0; // val = 0.0f for padded slots
    }
#pragma unroll
    for (int u = 0; u < 8; ++u)
      g[u] = *(const gvec*)(src + (size_t)cv[u].x * STRIDE + lo);
#pragma unroll
    for (int u = 0; u < 8; ++u) {
      float v = __int_as_float(cv[u].y);
#pragma unroll
      for (int q = 0; q < NCH; ++q) {
        a[2 * q] = fmaf(v, __builtin_bit_cast(float, g[u][q] << 16), a[2 * q]);
        a[2 * q + 1] =
            fmaf(v, __builtin_bit_cast(float, g[u][q] & 0xffff0000u), a[2 * q + 1]);
      }
    }
  }
  gvec o;
#pragma unroll
  for (int q = 0; q < NCH; ++q) o[q] = bf16_pack(a[2 * q], a[2 * q + 1]);
  *(gvec*)(dst + (size_t)r * STRIDE + lo) = o;
}

// ---- GEMM: out[i*NN+n][f] (+)= sum_k A[n][k] * wb[i*128+f][k] ----
// BK=64: 16KB As + 16KB Bs, 16 barriers, 8 GLDS16/thread in flight.
// XOR-swizzle 16B-chunk index by (row&7) on the GLOBAL source.
template <int KTOT, int HOPW, int ACCUM>
__global__ __launch_bounds__(256) void k_gemm(
    const uint16_t* __restrict__ h0, const uint16_t* __restrict__ h1,
    const uint16_t* __restrict__ h2, const uint16_t* __restrict__ h3,
    const uint16_t* __restrict__ wb, float* __restrict__ out) {
  __shared__ __align__(16) uint16_t As[128 * 64];
  __shared__ __align__(16) uint16_t Bs[128 * 64];
  const uint16_t* hops[4] = {h0, h1, h2, h3};
  int t = threadIdx.x;
  int lane = t & 63, wid = t >> 6;
  int wm = wid >> 1, wn = wid & 1;
  int m0 = blockIdx.x * 128;
  int c0 = blockIdx.y * 128;
  int rl = lane & 15, q = lane >> 4;
  f32x4 acc[4][4] = {};
#pragma unroll
  for (int hop = 0; hop < KTOT / HOPW; ++hop) {
    const uint16_t* hm = hops[hop];
#pragma unroll
    for (int kin = 0; kin < HOPW; kin += 64) {
      int k0 = hop * HOPW + kin;
#pragma unroll
      for (int rr = 0; rr < 4; ++rr) { // stage A: 1024 chunks of 16B
        int c = rr * 256 + t;
        int row = c >> 3, kcL = c & 7;
        int kcG = kcL ^ (row & 7); // swizzle on global source
        int gr = m0 + row;
        gr = gr < NN ? gr : NN - 1; // clamp (dup row harmless, store guarded)
        GLDS16(hm + (size_t)gr * HOPW + kin + kcG * 8, &As[c * 8]);
      }
#pragma unroll
      for (int rr = 0; rr < 4; ++rr) { // stage B
        int c = rr * 256 + t;
        int cc = c >> 3, kcL = c & 7;
        int kcG = kcL ^ (cc & 7);
        GLDS16(wb + (size_t)(c0 + cc) * KTOT + k0 + kcG * 8, &Bs[c * 8]);
      }
      __syncthreads();
#pragma unroll
      for (int kq2 = 0; kq2 < 2; ++kq2) { // two K=32 halves of BK=64
        int w = kq2 * 4 + q;              // wanted 16B chunk 0..7
        bf16x8 af[4], bq[4];
#pragma unroll
        for (int f = 0; f < 4; ++f) {
          int row = wm * 64 + f * 16 + rl;
          af[f] = *(const bf16x8*)(&As[row * 64 + (w ^ (row & 7)) * 8]);
          int col = wn * 64 + f * 16 + rl;
          bq[f] = *(const bf16x8*)(&Bs[col * 64 + (w ^ (col & 7)) * 8]);
        }
#pragma unroll
        for (int fm = 0; fm < 4; ++fm)
#pragma unroll
          for (int fn = 0; fn < 4; ++fn)
            acc[fm][fn] = __builtin_amdgcn_mfma_f32_16x16x32_bf16(af[fm], bq[fn],
                                                                  acc[fm][fn], 0, 0, 0);
      }
      __syncthreads();
    }
  }
  int iOut = blockIdx.y;
#pragma unroll
  for (int fm = 0; fm < 4; ++fm) {
#pragma unroll
    for (int r = 0; r < 4; ++r) {
      int rowg = m0 + wm * 64 + fm * 16 + q * 4 + r;
      if (rowg >= NN) continue;
      float* op = out + ((size_t)iOut * NN + rowg) * D;
#pragma unroll
      for (int fn = 0; fn < 4; ++fn) {
        int colg = wn * 64 + fn * 16 + rl;
        if (ACCUM)
          op[colg] += acc[fm][fn][r];
        else
          op[colg] = acc[fm][fn][r];
      }
    }
  }
}

extern "C" void kernel_launch(void* const* d_in, const int* in_sizes, int n_in,
                              void* d_out, int out_size, void* d_ws, size_t ws_size,
                              hipStream_t stream) {
  (void)in_sizes; (void)n_in; (void)out_size;
  const float* x = (const float*)d_in[0];      // [2, N, 128]
  const int* ei = (const int*)d_in[1];         // [2, E]
  const float* W = (const float*)d_in[2];      // [2, 2, 128, 128]
  const float* params = (const float*)d_in[3]; // [2, 2, 4]
  float* out = (float*)d_out;                  // [2, N, 128]
  char* ws = (char*)d_ws;

  size_t off = 0;
  auto take = [&](size_t bytes) {
    char* p = ws + off;
    off = (off + bytes + 255) & ~(size_t)255;
    return p;
  };
  int* deg = (int*)take((size_t)NN * 4);
  float* dinv = (float*)take((size_t)NN * 4);
  int* rp = (int*)take((size_t)(NN + 1) * 4);
  int* cur = (int*)take((size_t)NN * 4);
  int* bsum = (int*)take(256 * 4);
  int2* csr = (int2*)take((size_t)NE * 8);
  uint16_t* wb = (uint16_t*)take((size_t)256 * 1024 * 2); // 512 KB
  size_t fixed = off;

  hipMemsetAsync(deg, 0, (size_t)NN * 4, stream);
  k_deg<<<(NE + 255) / 256, 256, 0, stream>>>(ei, deg);
  k_dinv_bsum<<<SCAN_B, 256, 0, stream>>>(deg, dinv, bsum);
  k_rpwrite<<<SCAN_B, 256, 0, stream>>>(deg, bsum, rp, cur);
  k_scatter<<<(NE + 255) / 256, 256, 0, stream>>>(ei, ei + NE, dinv, cur, csr);

  size_t hopC = (size_t)NN * 256 * 2; // 25.6 MB per hop, combined channels
  size_t needC = fixed + 4 * hopC + 1024;

  if (ws_size >= needC) {
    // ---- fused-channel path: 3 spmm + 1 GEMM (K=1024) ----
    uint16_t* hop[4];
    for (int m = 0; m < 4; ++m) hop[m] = (uint16_t*)take(hopC);
    k_prep_c<<<XB + 1024, 256, 0, stream>>>(x, W, params, hop[0], wb);
    for (int m = 1; m <= KH; ++m)
      k_spmm<2><<<(NN + 3) / 4, 256, 0, stream>>>(rp, csr, hop[m - 1], hop[m]);
    dim3 grid((NN + 127) / 128, 2);
    k_gemm<1024, 256, 0><<<grid, 256, 0, stream>>>(hop[0], hop[1], hop[2], hop[3],
                                                   wb, out);
  } else {
    // ---- fallback: per-channel hops, 2 GEMMs ----
    size_t hopF = (size_t)NN * 128 * 2;
    uint16_t* hop[4];
    for (int m = 0; m < 4; ++m) hop[m] = (uint16_t*)take(hopF);
    k_wbig_f<<<(2 * 256 * 512 + 255) / 256, 256, 0, stream>>>(W, params, wb);
    for (int j = 0; j < 2; ++j) {
      k_x2h_f<<<(NN * D + 255) / 256, 256, 0, stream>>>(x + (size_t)j * NN * D, hop[0]);
      for (int m = 1; m <= KH; ++m)
        k_spmm<1><<<(NN + 3) / 4, 256, 0, stream>>>(rp, csr, hop[m - 1], hop[m]);
      dim3 grid((NN + 127) / 128, 2);
      if (j == 0)
        k_gemm<512, 128, 0><<<grid, 256, 0, stream>>>(hop[0], hop[1], hop[2], hop[3],
                                                      wb, out);
      else
        k_gemm<512, 128, 1><<<grid, 256, 0, stream>>>(hop[0], hop[1], hop[2], hop[3],
                                                      wb + 256 * 512, out);
    }
  }
}